// Round 4
// baseline (1181.134 us; speedup 1.0000x reference)
//
#include <hip/hip_runtime.h>

#define NN 50000
#define NE 800000
#define NG 128
#define OUTC 10
#define SCAN_NB ((NN + 255) / 256)  // 196
#define NTILE 3125                  // 50000 / 16 exactly

// ---------------------------------------------------------------- CSR build
__global__ void count_kernel(const int* __restrict__ dst, int* __restrict__ cnt) {
  for (int e = blockIdx.x * blockDim.x + threadIdx.x; e < NE; e += gridDim.x * blockDim.x)
    atomicAdd(&cnt[dst[e]], 1);
}

__global__ __launch_bounds__(256) void partial_kernel(const int* __restrict__ cnt,
                                                      int* __restrict__ part) {
  __shared__ int red[256];
  const int t = threadIdx.x;
  const int idx = blockIdx.x * 256 + t;
  red[t] = (idx < NN) ? cnt[idx] : 0;
  __syncthreads();
#pragma unroll
  for (int off = 128; off > 0; off >>= 1) {
    if (t < off) red[t] += red[t + off];
    __syncthreads();
  }
  if (t == 0) part[blockIdx.x] = red[0];
}

__global__ __launch_bounds__(256) void scanpart_kernel(int* __restrict__ part) {
  __shared__ int s[256];
  const int t = threadIdx.x;
  s[t] = (t < SCAN_NB) ? part[t] : 0;
  __syncthreads();
#pragma unroll
  for (int off = 1; off < 256; off <<= 1) {
    const int v = (t >= off) ? s[t - off] : 0;
    __syncthreads();
    s[t] += v;
    __syncthreads();
  }
  if (t < SCAN_NB) part[t] = (t == 0) ? 0 : s[t - 1];
}

__global__ __launch_bounds__(256) void scatter_scan_kernel(const int* __restrict__ cnt,
                                                           const int* __restrict__ part,
                                                           int* __restrict__ rowptr,
                                                           int* __restrict__ cursor) {
  __shared__ int s[256];
  const int t = threadIdx.x;
  const int idx = blockIdx.x * 256 + t;
  s[t] = (idx < NN) ? cnt[idx] : 0;
  __syncthreads();
#pragma unroll
  for (int off = 1; off < 256; off <<= 1) {
    const int v = (t >= off) ? s[t - off] : 0;
    __syncthreads();
    s[t] += v;
    __syncthreads();
  }
  const int excl = part[blockIdx.x] + ((t == 0) ? 0 : s[t - 1]);
  if (idx < NN) { rowptr[idx] = excl; cursor[idx] = excl; }
  if (idx == 0) rowptr[NN] = NE;
}

__global__ void fill_kernel(const int* __restrict__ src, const int* __restrict__ dst,
                            int* __restrict__ cursor, int* __restrict__ esrc) {
  for (int e = blockIdx.x * blockDim.x + threadIdx.x; e < NE; e += gridDim.x * blockDim.x) {
    int p = atomicAdd(&cursor[dst[e]], 1);
    esrc[p] = src[e];
  }
}

// ------------------------------------------------------- proj: y = x @ W1_0
__global__ __launch_bounds__(256) void proj_kernel(const float* __restrict__ x,
                                                   const float* __restrict__ w1,
                                                   float* __restrict__ y) {
  __shared__ float sW[128 * 64];
  __shared__ float sX[64 * 128];
  const int t = threadIdx.x, c = t & 63, rg = t >> 6;
  for (int i = t; i < 128 * 64; i += 256) sW[i] = w1[i];
  const int ntiles = (NN + 63) / 64;
  for (int tile = blockIdx.x; tile < ntiles; tile += gridDim.x) {
    const int r0 = tile * 64, nv = min(64, NN - r0);
    __syncthreads();
    for (int i = t; i < nv * 32; i += 256)
      ((float4*)sX)[i] = ((const float4*)(x + (size_t)r0 * 128))[i];
    __syncthreads();
    float acc[16];
#pragma unroll
    for (int i = 0; i < 16; ++i) acc[i] = 0.f;
    for (int k = 0; k < 128; k += 4) {
      const float w0 = sW[(k + 0) * 64 + c], w1v = sW[(k + 1) * 64 + c],
                  w2v = sW[(k + 2) * 64 + c], w3v = sW[(k + 3) * 64 + c];
#pragma unroll
      for (int i = 0; i < 16; ++i) {
        const float4 xv = *(const float4*)&sX[(rg * 16 + i) * 128 + k];
        acc[i] = fmaf(xv.x, w0, acc[i]);
        acc[i] = fmaf(xv.y, w1v, acc[i]);
        acc[i] = fmaf(xv.z, w2v, acc[i]);
        acc[i] = fmaf(xv.w, w3v, acc[i]);
      }
    }
#pragma unroll
    for (int i = 0; i < 16; ++i) {
      const int r = rg * 16 + i;
      if (r < nv) y[(size_t)(r0 + r) * 64 + c] = acc[i];
    }
  }
}

// ---------------------------------------------------- gather: z = A h + h
// POOL: also accumulate per-graph sum of h (the JK pooling, hoisted here since
// pooling commutes with the linear JK projection).
template <bool POOL>
__global__ __launch_bounds__(256, 8) void agg_kernel(const float* __restrict__ h,
                                                     const int* __restrict__ rowptr,
                                                     const int* __restrict__ esrc,
                                                     float* __restrict__ z,
                                                     const int* __restrict__ batch,
                                                     float* __restrict__ gl) {
  const int ln = threadIdx.x & 63, wv = threadIdx.x >> 6;
  const int q = ln >> 4, i = ln & 15;
  const int row = blockIdx.x * 4 + wv;
  if (row >= NN) return;
  const int beg = rowptr[row], end = rowptr[row + 1];
  float4 acc = {0.f, 0.f, 0.f, 0.f};
  float4 self = {0.f, 0.f, 0.f, 0.f};
  if (q == 0) { self = *(const float4*)&h[(size_t)row * 64 + i * 4]; acc = self; }
  int e = beg + q;
  for (; e + 12 < end; e += 16) {
    const int s0 = esrc[e];
    const int s1 = esrc[e + 4];
    const int s2 = esrc[e + 8];
    const int s3 = esrc[e + 12];
    const float4 v0 = *(const float4*)&h[(size_t)s0 * 64 + i * 4];
    const float4 v1 = *(const float4*)&h[(size_t)s1 * 64 + i * 4];
    const float4 v2 = *(const float4*)&h[(size_t)s2 * 64 + i * 4];
    const float4 v3 = *(const float4*)&h[(size_t)s3 * 64 + i * 4];
    acc.x += (v0.x + v1.x) + (v2.x + v3.x);
    acc.y += (v0.y + v1.y) + (v2.y + v3.y);
    acc.z += (v0.z + v1.z) + (v2.z + v3.z);
    acc.w += (v0.w + v1.w) + (v2.w + v3.w);
  }
  for (; e + 4 < end; e += 8) {
    const int s0 = esrc[e];
    const int s1 = esrc[e + 4];
    const float4 v0 = *(const float4*)&h[(size_t)s0 * 64 + i * 4];
    const float4 v1 = *(const float4*)&h[(size_t)s1 * 64 + i * 4];
    acc.x += v0.x + v1.x;
    acc.y += v0.y + v1.y;
    acc.z += v0.z + v1.z;
    acc.w += v0.w + v1.w;
  }
  for (; e < end; e += 4) {
    const int s = esrc[e];
    const float4 v = *(const float4*)&h[(size_t)s * 64 + i * 4];
    acc.x += v.x; acc.y += v.y; acc.z += v.z; acc.w += v.w;
  }
#pragma unroll
  for (int off = 16; off < 64; off <<= 1) {
    acc.x += __shfl_xor(acc.x, off);
    acc.y += __shfl_xor(acc.y, off);
    acc.z += __shfl_xor(acc.z, off);
    acc.w += __shfl_xor(acc.w, off);
  }
  if (q == 0) {
    *(float4*)&z[(size_t)row * 64 + i * 4] = acc;
    if (POOL) {
      const int b = batch[row];
      float* gp = &gl[(size_t)b * 64 + i * 4];
      atomicAdd(gp + 0, self.x);
      atomicAdd(gp + 1, self.y);
      atomicAdd(gp + 2, self.z);
      atomicAdd(gp + 3, self.w);
    }
  }
}

// -------------------------------------------------- MLP per layer (no JK now)
// Wave-local: each wave owns a 16-row tile, private LDS slice, NO barriers.
// HASW1: h = relu(relu(z@W1+b1)@W2+b2); else: h = relu(relu(z+b1)@W2+b2)
template <bool HASW1>
__global__ __launch_bounds__(256) void mlp_kernel(
    const float* __restrict__ z, const float* __restrict__ w1,
    const float* __restrict__ b1, const float* __restrict__ w2,
    const float* __restrict__ b2, float* __restrict__ hout) {
  __shared__ float sS[4][16 * 64];  // 16KB -> 4 blocks/CU
  const int t = threadIdx.x, c = t & 63, wv = t >> 6;
  const int wg = blockIdx.x * 4 + wv;
  if (wg >= NTILE) return;  // no barriers anywhere: safe
  float* slice = &sS[wv][0];
  const int n0 = wg * 16;
  const float b1c = b1[c], b2c = b2[c];

  // stage z rows -> LDS slice (coalesced b32 loads)
  float zr[16];
#pragma unroll
  for (int r = 0; r < 16; ++r) zr[r] = z[(size_t)(n0 + r) * 64 + c];
  if (!HASW1) {
#pragma unroll
    for (int r = 0; r < 16; ++r) zr[r] = fmaxf(zr[r] + b1c, 0.f);
  }
#pragma unroll
  for (int r = 0; r < 16; ++r) slice[r * 64 + c] = zr[r];

  // matvec1: h1 = relu(z @ W1 + b1)  (weights streamed from L2 in 16-k chunks)
  if (HASW1) {
    float acc[16];
#pragma unroll
    for (int r = 0; r < 16; ++r) acc[r] = b1c;
    for (int kc = 0; kc < 4; ++kc) {
      float wr[16];
#pragma unroll
      for (int j = 0; j < 16; ++j) wr[j] = w1[(kc * 16 + j) * 64 + c];
#pragma unroll
      for (int r = 0; r < 16; ++r) {
        const float* zp = &slice[r * 64 + kc * 16];
        const float4 za = *(const float4*)(zp + 0);
        const float4 zb = *(const float4*)(zp + 4);
        const float4 zc = *(const float4*)(zp + 8);
        const float4 zd = *(const float4*)(zp + 12);
        float a = acc[r];
        a = fmaf(za.x, wr[0], a);  a = fmaf(za.y, wr[1], a);
        a = fmaf(za.z, wr[2], a);  a = fmaf(za.w, wr[3], a);
        a = fmaf(zb.x, wr[4], a);  a = fmaf(zb.y, wr[5], a);
        a = fmaf(zb.z, wr[6], a);  a = fmaf(zb.w, wr[7], a);
        a = fmaf(zc.x, wr[8], a);  a = fmaf(zc.y, wr[9], a);
        a = fmaf(zc.z, wr[10], a); a = fmaf(zc.w, wr[11], a);
        a = fmaf(zd.x, wr[12], a); a = fmaf(zd.y, wr[13], a);
        a = fmaf(zd.z, wr[14], a); a = fmaf(zd.w, wr[15], a);
        acc[r] = a;
      }
    }
#pragma unroll
    for (int r = 0; r < 16; ++r) slice[r * 64 + c] = fmaxf(acc[r], 0.f);
  }

  // matvec2: h = relu(h1 @ W2 + b2) -> global
  float acc2[16];
#pragma unroll
  for (int r = 0; r < 16; ++r) acc2[r] = b2c;
  for (int kc = 0; kc < 4; ++kc) {
    float wr[16];
#pragma unroll
    for (int j = 0; j < 16; ++j) wr[j] = w2[(kc * 16 + j) * 64 + c];
#pragma unroll
    for (int r = 0; r < 16; ++r) {
      const float* hp = &slice[r * 64 + kc * 16];
      const float4 za = *(const float4*)(hp + 0);
      const float4 zb = *(const float4*)(hp + 4);
      const float4 zc = *(const float4*)(hp + 8);
      const float4 zd = *(const float4*)(hp + 12);
      float a = acc2[r];
      a = fmaf(za.x, wr[0], a);  a = fmaf(za.y, wr[1], a);
      a = fmaf(za.z, wr[2], a);  a = fmaf(za.w, wr[3], a);
      a = fmaf(zb.x, wr[4], a);  a = fmaf(zb.y, wr[5], a);
      a = fmaf(zb.z, wr[6], a);  a = fmaf(zb.w, wr[7], a);
      a = fmaf(zc.x, wr[8], a);  a = fmaf(zc.y, wr[9], a);
      a = fmaf(zc.z, wr[10], a); a = fmaf(zc.w, wr[11], a);
      a = fmaf(zd.x, wr[12], a); a = fmaf(zd.y, wr[13], a);
      a = fmaf(zd.z, wr[14], a); a = fmaf(zd.w, wr[15], a);
      acc2[r] = a;
    }
  }
#pragma unroll
  for (int r = 0; r < 16; ++r)
    hout[(size_t)(n0 + r) * 64 + c] = fmaxf(acc2[r], 0.f);
}

// ------------------------------------------- pool h5 + per-graph node counts
__global__ __launch_bounds__(256) void pool_kernel(const float* __restrict__ h5,
                                                   const int* __restrict__ batch,
                                                   float* __restrict__ g5last,
                                                   float* __restrict__ gcnt) {
  const int wgid = blockIdx.x * 4 + (threadIdx.x >> 6);
  const int c = threadIdx.x & 63;
  const int W = gridDim.x * 4;
  const int chunk = (NN + W - 1) / W;
  const int n0 = wgid * chunk, n1 = min(n0 + chunk, NN);
  if (n0 >= n1) return;
  float acc = 0.f, cn = 0.f;
  int cur = batch[n0];
  for (int n = n0; n < n1; ++n) {
    const int b = batch[n];
    const float v = h5[(size_t)n * 64 + c];
    if (b != cur) {
      atomicAdd(&g5last[cur * 64 + c], acc);
      if (c == 0) atomicAdd(&gcnt[cur], cn);
      acc = 0.f; cn = 0.f; cur = b;
    }
    acc += v;
    cn += 1.f;
  }
  atomicAdd(&g5last[cur * 64 + c], acc);
  if (c == 0) atomicAdd(&gcnt[cur], cn);
}

// ------------------------------------------------------------- classifier
// g = sum_l g5[l] @ WJ_l + cnt*jk_b ; t = g@W1+b1 ; BN ; relu ; out = t@W2+b2
__global__ __launch_bounds__(1024) void classifier_kernel(
    const float* __restrict__ g5, const float* __restrict__ gcnt,
    const float* __restrict__ jkw, const float* __restrict__ jkb,
    const float* __restrict__ w1, const float* __restrict__ b1,
    const float* __restrict__ gamma, const float* __restrict__ beta,
    const float* __restrict__ w2, const float* __restrict__ b2,
    float* __restrict__ out) {
  __shared__ float smem[20480 + 8192 + 4096 + 768 + 128];
  float* sWJ = smem;            // [320*64]  (reused as sT after the fold)
  float* sG  = smem + 20480;    // [128*64]
  float* sW1 = smem + 28672;    // [64*64]
  float* sW2 = smem + 32768;    // [64*OUTC]
  float* sMu = smem + 33536;    // [64]
  float* sRs = smem + 33600;    // [64]
  float* sT  = smem;            // alias of sWJ (valid after fold + barrier)
  const int t = threadIdx.x, c = t & 63, gsub = t >> 6;  // 16 graphs/pass
  for (int i = t; i < 320 * 64; i += 1024) sWJ[i] = jkw[i];
  for (int i = t; i < 64 * 64; i += 1024) sW1[i] = w1[i];
  for (int i = t; i < 64 * OUTC; i += 1024) sW2[i] = w2[i];
  __syncthreads();
  // JK fold -> sG
  const float bjc = jkb[c];
#pragma unroll
  for (int p = 0; p < 8; ++p) {
    const int gi = p * 16 + gsub;
    float a = bjc * gcnt[gi];
    for (int l = 0; l < 5; ++l) {
      const float* gv = &g5[(size_t)(l * NG + gi) * 64];
      const float* wv = &sWJ[l * 4096];
      for (int k = 0; k < 64; k += 4) {
        a = fmaf(gv[k + 0], wv[(k + 0) * 64 + c], a);
        a = fmaf(gv[k + 1], wv[(k + 1) * 64 + c], a);
        a = fmaf(gv[k + 2], wv[(k + 2) * 64 + c], a);
        a = fmaf(gv[k + 3], wv[(k + 3) * 64 + c], a);
      }
    }
    sG[gi * 64 + c] = a;
  }
  __syncthreads();
  // t = G @ W1 + b1 -> sT (overwrites sWJ, done with it)
  const float b1c = b1[c];
#pragma unroll
  for (int p = 0; p < 8; ++p) {
    const int gi = p * 16 + gsub;
    float a = b1c;
    for (int k = 0; k < 64; ++k) a = fmaf(sG[gi * 64 + k], sW1[k * 64 + c], a);
    sT[gi * 64 + c] = a;
  }
  __syncthreads();
  if (t < 64) {
    float s = 0.f;
    for (int gi = 0; gi < NG; ++gi) s += sT[gi * 64 + t];
    const float mu = s / NG;
    float v = 0.f;
    for (int gi = 0; gi < NG; ++gi) { const float d = sT[gi * 64 + t] - mu; v += d * d; }
    v /= NG;
    sMu[t] = mu;
    sRs[t] = rsqrtf(v + 1e-5f);
  }
  __syncthreads();
  for (int idx = t; idx < NG * 64; idx += 1024) {
    const int cc = idx & 63;
    sT[idx] = fmaxf((sT[idx] - sMu[cc]) * sRs[cc] * gamma[cc] + beta[cc], 0.f);
  }
  __syncthreads();
  for (int idx = t; idx < NG * OUTC; idx += 1024) {
    const int gi = idx / OUTC, o = idx % OUTC;
    float a = b2[o];
    for (int k = 0; k < 64; ++k) a = fmaf(sT[gi * 64 + k], sW2[k * OUTC + o], a);
    out[idx] = a;
  }
}

// ---------------------------------------------------------------- launch
extern "C" void kernel_launch(void* const* d_in, const int* in_sizes, int n_in,
                              void* d_out, int out_size, void* d_ws, size_t ws_size,
                              hipStream_t stream) {
  const float* x     = (const float*)d_in[0];
  const int*   ei    = (const int*)d_in[1];
  const int*   batch = (const int*)d_in[2];
  const float* w1_0  = (const float*)d_in[3];
  const float* b1_0  = (const float*)d_in[4];
  const float* w2_0  = (const float*)d_in[5];
  const float* b2_0  = (const float*)d_in[6];
  const float* w1_r  = (const float*)d_in[7];
  const float* b1_r  = (const float*)d_in[8];
  const float* w2_r  = (const float*)d_in[9];
  const float* b2_r  = (const float*)d_in[10];
  const float* jk_w  = (const float*)d_in[11];
  const float* jk_b  = (const float*)d_in[12];
  const float* cw1   = (const float*)d_in[13];
  const float* cb1   = (const float*)d_in[14];
  const float* bng   = (const float*)d_in[15];
  const float* bnb   = (const float*)d_in[16];
  const float* cw2   = (const float*)d_in[17];
  const float* cb2   = (const float*)d_in[18];
  float* out = (float*)d_out;

  char* base = (char*)d_ws;
  size_t o = 0;
  auto take = [&](size_t n) { char* p = base + o; o = (o + n + 255) & ~(size_t)255; return p; };
  int*   cnt    = (int*)take((size_t)NN * 4);
  int*   rowptr = (int*)take((size_t)(NN + 1) * 4);
  int*   cursor = (int*)take((size_t)NN * 4);
  int*   part   = (int*)take((size_t)SCAN_NB * 4);
  int*   esrc   = (int*)take((size_t)NE * 4);
  float* hA     = (float*)take((size_t)NN * 64 * 4);
  float* hB     = (float*)take((size_t)NN * 64 * 4);
  float* z      = (float*)take((size_t)NN * 64 * 4);
  float* g5     = (float*)take((size_t)5 * NG * 64 * 4);
  float* gcnt   = (float*)take((size_t)NG * 4);
  (void)ws_size; (void)in_sizes; (void)n_in; (void)out_size;

  hipMemsetAsync(cnt, 0, (size_t)NN * 4, stream);
  hipMemsetAsync(g5, 0, (size_t)5 * NG * 64 * 4, stream);
  hipMemsetAsync(gcnt, 0, (size_t)NG * 4, stream);

  const int* src = ei;
  const int* dst = ei + NE;
  count_kernel<<<1024, 256, 0, stream>>>(dst, cnt);
  partial_kernel<<<SCAN_NB, 256, 0, stream>>>(cnt, part);
  scanpart_kernel<<<1, 256, 0, stream>>>(part);
  scatter_scan_kernel<<<SCAN_NB, 256, 0, stream>>>(cnt, part, rowptr, cursor);
  fill_kernel<<<1024, 256, 0, stream>>>(src, dst, cursor, esrc);

  const int MLP_GRID = (NTILE + 3) / 4;  // 782

  // layer 0 (pre-projected): y = x@W1_0 (into hB), z = A y + y, MLP w/o W1
  proj_kernel<<<512, 256, 0, stream>>>(x, w1_0, hB);
  agg_kernel<false><<<(NN + 3) / 4, 256, 0, stream>>>(hB, rowptr, esrc, z, nullptr, nullptr);
  mlp_kernel<false><<<MLP_GRID, 256, 0, stream>>>(z, nullptr, b1_0, w2_0, b2_0, hA);
  const float* hin = hA;
  float* hout = hB;
  for (int l = 1; l < 5; ++l) {
    // agg of layer l reads xs[l-1]: pool it into g5[l-1] on the way
    agg_kernel<true><<<(NN + 3) / 4, 256, 0, stream>>>(hin, rowptr, esrc, z, batch,
                                                       g5 + (size_t)(l - 1) * NG * 64);
    mlp_kernel<true><<<MLP_GRID, 256, 0, stream>>>(
        z, w1_r + (size_t)(l - 1) * 64 * 64, b1_r + (size_t)(l - 1) * 64,
        w2_r + (size_t)(l - 1) * 64 * 64, b2_r + (size_t)(l - 1) * 64, hout);
    float* tmp = (float*)hin;
    hin = hout;
    hout = tmp;
  }

  // pool h5 (= hin after the loop) + node counts
  pool_kernel<<<256, 256, 0, stream>>>(hin, batch, g5 + (size_t)4 * NG * 64, gcnt);
  classifier_kernel<<<1, 1024, 0, stream>>>(g5, gcnt, jk_w, jk_b, cw1, cb1, bng, bnb,
                                            cw2, cb2, out);
}

// Round 5
// 490.656 us; speedup vs baseline: 2.4073x; 2.4073x over previous
//
#include <hip/hip_runtime.h>

#define NN 50000
#define NE 800000
#define NG 128
#define OUTC 10
#define SCAN_NB ((NN + 255) / 256)  // 196
#define NTILE 3125                  // 50000 / 16 exactly

// ---------------------------------------------------------------- CSR build
__global__ void count_kernel(const int* __restrict__ dst, int* __restrict__ cnt) {
  for (int e = blockIdx.x * blockDim.x + threadIdx.x; e < NE; e += gridDim.x * blockDim.x)
    atomicAdd(&cnt[dst[e]], 1);
}

__global__ __launch_bounds__(256) void partial_kernel(const int* __restrict__ cnt,
                                                      int* __restrict__ part) {
  __shared__ int red[256];
  const int t = threadIdx.x;
  const int idx = blockIdx.x * 256 + t;
  red[t] = (idx < NN) ? cnt[idx] : 0;
  __syncthreads();
#pragma unroll
  for (int off = 128; off > 0; off >>= 1) {
    if (t < off) red[t] += red[t + off];
    __syncthreads();
  }
  if (t == 0) part[blockIdx.x] = red[0];
}

__global__ __launch_bounds__(256) void scanpart_kernel(int* __restrict__ part) {
  __shared__ int s[256];
  const int t = threadIdx.x;
  s[t] = (t < SCAN_NB) ? part[t] : 0;
  __syncthreads();
#pragma unroll
  for (int off = 1; off < 256; off <<= 1) {
    const int v = (t >= off) ? s[t - off] : 0;
    __syncthreads();
    s[t] += v;
    __syncthreads();
  }
  if (t < SCAN_NB) part[t] = (t == 0) ? 0 : s[t - 1];
}

__global__ __launch_bounds__(256) void scatter_scan_kernel(const int* __restrict__ cnt,
                                                           const int* __restrict__ part,
                                                           int* __restrict__ rowptr,
                                                           int* __restrict__ cursor) {
  __shared__ int s[256];
  const int t = threadIdx.x;
  const int idx = blockIdx.x * 256 + t;
  s[t] = (idx < NN) ? cnt[idx] : 0;
  __syncthreads();
#pragma unroll
  for (int off = 1; off < 256; off <<= 1) {
    const int v = (t >= off) ? s[t - off] : 0;
    __syncthreads();
    s[t] += v;
    __syncthreads();
  }
  const int excl = part[blockIdx.x] + ((t == 0) ? 0 : s[t - 1]);
  if (idx < NN) { rowptr[idx] = excl; cursor[idx] = excl; }
  if (idx == 0) rowptr[NN] = NE;
}

__global__ void fill_kernel(const int* __restrict__ src, const int* __restrict__ dst,
                            int* __restrict__ cursor, int* __restrict__ esrc) {
  for (int e = blockIdx.x * blockDim.x + threadIdx.x; e < NE; e += gridDim.x * blockDim.x) {
    int p = atomicAdd(&cursor[dst[e]], 1);
    esrc[p] = src[e];
  }
}

// ------------------------------------- per-graph node counts (batch sorted)
__global__ __launch_bounds__(128) void gbounds_kernel(const int* __restrict__ batch,
                                                      float* __restrict__ gcnt) {
  __shared__ int sb[NG + 1];
  const int g = threadIdx.x;
  int lo = 0, hi = NN;
  while (lo < hi) {
    const int mid = (lo + hi) >> 1;
    if (batch[mid] < g) lo = mid + 1; else hi = mid;
  }
  sb[g] = lo;
  if (g == 0) sb[NG] = NN;
  __syncthreads();
  gcnt[g] = (float)(sb[g + 1] - sb[g]);
}

// ------------------------------------------------------- proj: y = x @ W1_0
__global__ __launch_bounds__(256) void proj_kernel(const float* __restrict__ x,
                                                   const float* __restrict__ w1,
                                                   float* __restrict__ y) {
  __shared__ float sW[128 * 64];
  __shared__ float sX[64 * 128];
  const int t = threadIdx.x, c = t & 63, rg = t >> 6;
  for (int i = t; i < 128 * 64; i += 256) sW[i] = w1[i];
  const int ntiles = (NN + 63) / 64;
  for (int tile = blockIdx.x; tile < ntiles; tile += gridDim.x) {
    const int r0 = tile * 64, nv = min(64, NN - r0);
    __syncthreads();
    for (int i = t; i < nv * 32; i += 256)
      ((float4*)sX)[i] = ((const float4*)(x + (size_t)r0 * 128))[i];
    __syncthreads();
    float acc[16];
#pragma unroll
    for (int i = 0; i < 16; ++i) acc[i] = 0.f;
    for (int k = 0; k < 128; k += 4) {
      const float w0 = sW[(k + 0) * 64 + c], w1v = sW[(k + 1) * 64 + c],
                  w2v = sW[(k + 2) * 64 + c], w3v = sW[(k + 3) * 64 + c];
#pragma unroll
      for (int i = 0; i < 16; ++i) {
        const float4 xv = *(const float4*)&sX[(rg * 16 + i) * 128 + k];
        acc[i] = fmaf(xv.x, w0, acc[i]);
        acc[i] = fmaf(xv.y, w1v, acc[i]);
        acc[i] = fmaf(xv.z, w2v, acc[i]);
        acc[i] = fmaf(xv.w, w3v, acc[i]);
      }
    }
#pragma unroll
    for (int i = 0; i < 16; ++i) {
      const int r = rg * 16 + i;
      if (r < nv) y[(size_t)(r0 + r) * 64 + c] = acc[i];
    }
  }
}

// ---------------------------------------------------- gather: z = A h + h
// wave per row; quarter-wave (16 lanes x float4) per edge; no LDS, no atomics.
__global__ __launch_bounds__(256, 8) void agg_kernel(const float* __restrict__ h,
                                                     const int* __restrict__ rowptr,
                                                     const int* __restrict__ esrc,
                                                     float* __restrict__ z) {
  const int ln = threadIdx.x & 63, wv = threadIdx.x >> 6;
  const int q = ln >> 4, i = ln & 15;
  const int row = blockIdx.x * 4 + wv;
  if (row >= NN) return;
  const int beg = rowptr[row], end = rowptr[row + 1];
  float4 acc = {0.f, 0.f, 0.f, 0.f};
  if (q == 0) acc = *(const float4*)&h[(size_t)row * 64 + i * 4];  // self term
  int e = beg + q;
  for (; e + 12 < end; e += 16) {
    const int s0 = esrc[e];
    const int s1 = esrc[e + 4];
    const int s2 = esrc[e + 8];
    const int s3 = esrc[e + 12];
    const float4 v0 = *(const float4*)&h[(size_t)s0 * 64 + i * 4];
    const float4 v1 = *(const float4*)&h[(size_t)s1 * 64 + i * 4];
    const float4 v2 = *(const float4*)&h[(size_t)s2 * 64 + i * 4];
    const float4 v3 = *(const float4*)&h[(size_t)s3 * 64 + i * 4];
    acc.x += (v0.x + v1.x) + (v2.x + v3.x);
    acc.y += (v0.y + v1.y) + (v2.y + v3.y);
    acc.z += (v0.z + v1.z) + (v2.z + v3.z);
    acc.w += (v0.w + v1.w) + (v2.w + v3.w);
  }
  for (; e + 4 < end; e += 8) {
    const int s0 = esrc[e];
    const int s1 = esrc[e + 4];
    const float4 v0 = *(const float4*)&h[(size_t)s0 * 64 + i * 4];
    const float4 v1 = *(const float4*)&h[(size_t)s1 * 64 + i * 4];
    acc.x += v0.x + v1.x;
    acc.y += v0.y + v1.y;
    acc.z += v0.z + v1.z;
    acc.w += v0.w + v1.w;
  }
  for (; e < end; e += 4) {
    const int s = esrc[e];
    const float4 v = *(const float4*)&h[(size_t)s * 64 + i * 4];
    acc.x += v.x; acc.y += v.y; acc.z += v.z; acc.w += v.w;
  }
#pragma unroll
  for (int off = 16; off < 64; off <<= 1) {
    acc.x += __shfl_xor(acc.x, off);
    acc.y += __shfl_xor(acc.y, off);
    acc.z += __shfl_xor(acc.z, off);
    acc.w += __shfl_xor(acc.w, off);
  }
  if (q == 0) *(float4*)&z[(size_t)row * 64 + i * 4] = acc;
}

// ------------------------- MLP per layer + fused run-length pooling epilogue
// Wave-local: each wave owns a 16-row tile, private LDS slice, NO barriers.
// h = relu(relu(z@W1+b1)@W2+b2)  (layer 0 pre-projected: h1 = relu(z+b1))
// epilogue: gl[batch[n]] += h[n]  (batch sorted -> ~1 atomic flush per wave)
template <bool HASW1>
__global__ __launch_bounds__(256) void mlp_kernel(
    const float* __restrict__ z, const float* __restrict__ w1,
    const float* __restrict__ b1, const float* __restrict__ w2,
    const float* __restrict__ b2, float* __restrict__ hout,
    const int* __restrict__ batch, float* __restrict__ gl) {
  __shared__ float sS[4][16 * 64];  // 16KB -> 4 blocks/CU
  const int t = threadIdx.x, c = t & 63, wv = t >> 6;
  const int wg = blockIdx.x * 4 + wv;
  if (wg >= NTILE) return;  // no barriers anywhere: safe
  float* slice = &sS[wv][0];
  const int n0 = wg * 16;
  const float b1c = b1[c], b2c = b2[c];

  float zr[16];
#pragma unroll
  for (int r = 0; r < 16; ++r) zr[r] = z[(size_t)(n0 + r) * 64 + c];
  if (!HASW1) {
#pragma unroll
    for (int r = 0; r < 16; ++r) zr[r] = fmaxf(zr[r] + b1c, 0.f);
  }
#pragma unroll
  for (int r = 0; r < 16; ++r) slice[r * 64 + c] = zr[r];

  if (HASW1) {
    float acc[16];
#pragma unroll
    for (int r = 0; r < 16; ++r) acc[r] = b1c;
    for (int kc = 0; kc < 4; ++kc) {
      float wr[16];
#pragma unroll
      for (int j = 0; j < 16; ++j) wr[j] = w1[(kc * 16 + j) * 64 + c];
#pragma unroll
      for (int r = 0; r < 16; ++r) {
        const float* zp = &slice[r * 64 + kc * 16];
        const float4 za = *(const float4*)(zp + 0);
        const float4 zb = *(const float4*)(zp + 4);
        const float4 zc = *(const float4*)(zp + 8);
        const float4 zd = *(const float4*)(zp + 12);
        float a = acc[r];
        a = fmaf(za.x, wr[0], a);  a = fmaf(za.y, wr[1], a);
        a = fmaf(za.z, wr[2], a);  a = fmaf(za.w, wr[3], a);
        a = fmaf(zb.x, wr[4], a);  a = fmaf(zb.y, wr[5], a);
        a = fmaf(zb.z, wr[6], a);  a = fmaf(zb.w, wr[7], a);
        a = fmaf(zc.x, wr[8], a);  a = fmaf(zc.y, wr[9], a);
        a = fmaf(zc.z, wr[10], a); a = fmaf(zc.w, wr[11], a);
        a = fmaf(zd.x, wr[12], a); a = fmaf(zd.y, wr[13], a);
        a = fmaf(zd.z, wr[14], a); a = fmaf(zd.w, wr[15], a);
        acc[r] = a;
      }
    }
#pragma unroll
    for (int r = 0; r < 16; ++r) slice[r * 64 + c] = fmaxf(acc[r], 0.f);
  }

  float acc2[16];
#pragma unroll
  for (int r = 0; r < 16; ++r) acc2[r] = b2c;
  for (int kc = 0; kc < 4; ++kc) {
    float wr[16];
#pragma unroll
    for (int j = 0; j < 16; ++j) wr[j] = w2[(kc * 16 + j) * 64 + c];
#pragma unroll
    for (int r = 0; r < 16; ++r) {
      const float* hp = &slice[r * 64 + kc * 16];
      const float4 za = *(const float4*)(hp + 0);
      const float4 zb = *(const float4*)(hp + 4);
      const float4 zc = *(const float4*)(hp + 8);
      const float4 zd = *(const float4*)(hp + 12);
      float a = acc2[r];
      a = fmaf(za.x, wr[0], a);  a = fmaf(za.y, wr[1], a);
      a = fmaf(za.z, wr[2], a);  a = fmaf(za.w, wr[3], a);
      a = fmaf(zb.x, wr[4], a);  a = fmaf(zb.y, wr[5], a);
      a = fmaf(zb.z, wr[6], a);  a = fmaf(zb.w, wr[7], a);
      a = fmaf(zc.x, wr[8], a);  a = fmaf(zc.y, wr[9], a);
      a = fmaf(zc.z, wr[10], a); a = fmaf(zc.w, wr[11], a);
      a = fmaf(zd.x, wr[12], a); a = fmaf(zd.y, wr[13], a);
      a = fmaf(zd.z, wr[14], a); a = fmaf(zd.w, wr[15], a);
      acc2[r] = a;
    }
  }
  // store + fused pooling (run-length over sorted batch; wave-uniform branch)
  float pacc = 0.f;
  int cur = batch[n0];
#pragma unroll
  for (int r = 0; r < 16; ++r) {
    const float hval = fmaxf(acc2[r], 0.f);
    hout[(size_t)(n0 + r) * 64 + c] = hval;
    const int b = batch[n0 + r];
    if (b != cur) {
      atomicAdd(&gl[(size_t)cur * 64 + c], pacc);
      pacc = 0.f;
      cur = b;
    }
    pacc += hval;
  }
  atomicAdd(&gl[(size_t)cur * 64 + c], pacc);
}

// ---------------------- JK fold + first classifier matvec (1 graph / block)
// t[gi] = (sum_l g5[l][gi] @ WJ_l + gcnt[gi]*jk_b) @ W1 + b1
__global__ __launch_bounds__(64) void jk_fold_kernel(
    const float* __restrict__ g5, const float* __restrict__ gcnt,
    const float* __restrict__ jkw, const float* __restrict__ jkb,
    const float* __restrict__ w1, const float* __restrict__ b1,
    float* __restrict__ tmat) {
  __shared__ float sg[64];
  const int gi = blockIdx.x, c = threadIdx.x;
  float a = jkb[c] * gcnt[gi];
  for (int l = 0; l < 5; ++l) {
    const float* gv = &g5[(size_t)(l * NG + gi) * 64];
    const float* wv = &jkw[(size_t)l * 64 * 64];
#pragma unroll 8
    for (int k = 0; k < 64; ++k) a = fmaf(gv[k], wv[k * 64 + c], a);
  }
  sg[c] = a;
  __syncthreads();  // single wave, but cheap and safe
  float tv = b1[c];
#pragma unroll 8
  for (int k = 0; k < 64; ++k) tv = fmaf(sg[k], w1[k * 64 + c], tv);
  tmat[gi * 64 + c] = tv;
}

// --------------------------------------------- BN (batch stats) + out matvec
__global__ __launch_bounds__(256) void bn_out_kernel(
    const float* __restrict__ tmat, const float* __restrict__ gamma,
    const float* __restrict__ beta, const float* __restrict__ w2,
    const float* __restrict__ b2, float* __restrict__ out) {
  __shared__ float sT[NG * 64];
  __shared__ float sW2[64 * OUTC];
  __shared__ float sMu[64], sRs[64];
  const int t = threadIdx.x;
  for (int i = t; i < NG * 64; i += 256) sT[i] = tmat[i];
  for (int i = t; i < 64 * OUTC; i += 256) sW2[i] = w2[i];
  __syncthreads();
  if (t < 64) {
    float s = 0.f;
    for (int gi = 0; gi < NG; ++gi) s += sT[gi * 64 + t];
    const float mu = s / NG;
    float v = 0.f;
    for (int gi = 0; gi < NG; ++gi) { const float d = sT[gi * 64 + t] - mu; v += d * d; }
    v /= NG;
    sMu[t] = mu;
    sRs[t] = rsqrtf(v + 1e-5f);
  }
  __syncthreads();
  for (int idx = t; idx < NG * 64; idx += 256) {
    const int cc = idx & 63;
    sT[idx] = fmaxf((sT[idx] - sMu[cc]) * sRs[cc] * gamma[cc] + beta[cc], 0.f);
  }
  __syncthreads();
  for (int idx = t; idx < NG * OUTC; idx += 256) {
    const int gi = idx / OUTC, o = idx % OUTC;
    float a = b2[o];
    for (int k = 0; k < 64; ++k) a = fmaf(sT[gi * 64 + k], sW2[k * OUTC + o], a);
    out[idx] = a;
  }
}

// ---------------------------------------------------------------- launch
extern "C" void kernel_launch(void* const* d_in, const int* in_sizes, int n_in,
                              void* d_out, int out_size, void* d_ws, size_t ws_size,
                              hipStream_t stream) {
  const float* x     = (const float*)d_in[0];
  const int*   ei    = (const int*)d_in[1];
  const int*   batch = (const int*)d_in[2];
  const float* w1_0  = (const float*)d_in[3];
  const float* b1_0  = (const float*)d_in[4];
  const float* w2_0  = (const float*)d_in[5];
  const float* b2_0  = (const float*)d_in[6];
  const float* w1_r  = (const float*)d_in[7];
  const float* b1_r  = (const float*)d_in[8];
  const float* w2_r  = (const float*)d_in[9];
  const float* b2_r  = (const float*)d_in[10];
  const float* jk_w  = (const float*)d_in[11];
  const float* jk_b  = (const float*)d_in[12];
  const float* cw1   = (const float*)d_in[13];
  const float* cb1   = (const float*)d_in[14];
  const float* bng   = (const float*)d_in[15];
  const float* bnb   = (const float*)d_in[16];
  const float* cw2   = (const float*)d_in[17];
  const float* cb2   = (const float*)d_in[18];
  float* out = (float*)d_out;

  char* base = (char*)d_ws;
  size_t o = 0;
  auto take = [&](size_t n) { char* p = base + o; o = (o + n + 255) & ~(size_t)255; return p; };
  int*   cnt    = (int*)take((size_t)NN * 4);
  int*   rowptr = (int*)take((size_t)(NN + 1) * 4);
  int*   cursor = (int*)take((size_t)NN * 4);
  int*   part   = (int*)take((size_t)SCAN_NB * 4);
  int*   esrc   = (int*)take((size_t)NE * 4);
  float* hA     = (float*)take((size_t)NN * 64 * 4);
  float* hB     = (float*)take((size_t)NN * 64 * 4);
  float* z      = (float*)take((size_t)NN * 64 * 4);
  float* g5     = (float*)take((size_t)5 * NG * 64 * 4);
  float* gcnt   = (float*)take((size_t)NG * 4);
  float* tmat   = (float*)take((size_t)NG * 64 * 4);
  (void)ws_size; (void)in_sizes; (void)n_in; (void)out_size;

  hipMemsetAsync(cnt, 0, (size_t)NN * 4, stream);
  hipMemsetAsync(g5, 0, (size_t)5 * NG * 64 * 4, stream);

  const int* src = ei;
  const int* dst = ei + NE;
  count_kernel<<<1024, 256, 0, stream>>>(dst, cnt);
  partial_kernel<<<SCAN_NB, 256, 0, stream>>>(cnt, part);
  scanpart_kernel<<<1, 256, 0, stream>>>(part);
  scatter_scan_kernel<<<SCAN_NB, 256, 0, stream>>>(cnt, part, rowptr, cursor);
  fill_kernel<<<1024, 256, 0, stream>>>(src, dst, cursor, esrc);
  gbounds_kernel<<<1, 128, 0, stream>>>(batch, gcnt);

  const int MLP_GRID = (NTILE + 3) / 4;  // 782

  // layer 0 (pre-projected): y = x@W1_0 (into hB), z = A y + y, MLP w/o W1
  proj_kernel<<<512, 256, 0, stream>>>(x, w1_0, hB);
  agg_kernel<<<(NN + 3) / 4, 256, 0, stream>>>(hB, rowptr, esrc, z);
  mlp_kernel<false><<<MLP_GRID, 256, 0, stream>>>(z, nullptr, b1_0, w2_0, b2_0, hA,
                                                  batch, g5);
  const float* hin = hA;
  float* hout = hB;
  for (int l = 1; l < 5; ++l) {
    agg_kernel<<<(NN + 3) / 4, 256, 0, stream>>>(hin, rowptr, esrc, z);
    mlp_kernel<true><<<MLP_GRID, 256, 0, stream>>>(
        z, w1_r + (size_t)(l - 1) * 64 * 64, b1_r + (size_t)(l - 1) * 64,
        w2_r + (size_t)(l - 1) * 64 * 64, b2_r + (size_t)(l - 1) * 64, hout,
        batch, g5 + (size_t)l * NG * 64);
    float* tmp = (float*)hin;
    hin = hout;
    hout = tmp;
  }

  jk_fold_kernel<<<NG, 64, 0, stream>>>(g5, gcnt, jk_w, jk_b, cw1, cb1, tmat);
  bn_out_kernel<<<1, 256, 0, stream>>>(tmat, bng, bnb, cw2, cb2, out);
}

// Round 6
// 450.839 us; speedup vs baseline: 2.6199x; 1.0883x over previous
//
#include <hip/hip_runtime.h>
#include <hip/hip_fp16.h>

#define NN 50000
#define NE 800000
#define NG 128
#define OUTC 10
#define SCAN_NB ((NN + 255) / 256)  // 196
#define NTILE 3125                  // 50000 / 16 exactly

// ---------------------------------------------------------------- CSR build
__global__ void count_kernel(const int* __restrict__ dst, int* __restrict__ cnt) {
  for (int e = blockIdx.x * blockDim.x + threadIdx.x; e < NE; e += gridDim.x * blockDim.x)
    atomicAdd(&cnt[dst[e]], 1);
}

__global__ __launch_bounds__(256) void partial_kernel(const int* __restrict__ cnt,
                                                      int* __restrict__ part) {
  __shared__ int red[256];
  const int t = threadIdx.x;
  const int idx = blockIdx.x * 256 + t;
  red[t] = (idx < NN) ? cnt[idx] : 0;
  __syncthreads();
#pragma unroll
  for (int off = 128; off > 0; off >>= 1) {
    if (t < off) red[t] += red[t + off];
    __syncthreads();
  }
  if (t == 0) part[blockIdx.x] = red[0];
}

__global__ __launch_bounds__(256) void scanpart_kernel(int* __restrict__ part) {
  __shared__ int s[256];
  const int t = threadIdx.x;
  s[t] = (t < SCAN_NB) ? part[t] : 0;
  __syncthreads();
#pragma unroll
  for (int off = 1; off < 256; off <<= 1) {
    const int v = (t >= off) ? s[t - off] : 0;
    __syncthreads();
    s[t] += v;
    __syncthreads();
  }
  if (t < SCAN_NB) part[t] = (t == 0) ? 0 : s[t - 1];
}

__global__ __launch_bounds__(256) void scatter_scan_kernel(const int* __restrict__ cnt,
                                                           const int* __restrict__ part,
                                                           int* __restrict__ rowptr,
                                                           int* __restrict__ cursor) {
  __shared__ int s[256];
  const int t = threadIdx.x;
  const int idx = blockIdx.x * 256 + t;
  s[t] = (idx < NN) ? cnt[idx] : 0;
  __syncthreads();
#pragma unroll
  for (int off = 1; off < 256; off <<= 1) {
    const int v = (t >= off) ? s[t - off] : 0;
    __syncthreads();
    s[t] += v;
    __syncthreads();
  }
  const int excl = part[blockIdx.x] + ((t == 0) ? 0 : s[t - 1]);
  if (idx < NN) { rowptr[idx] = excl; cursor[idx] = excl; }
  if (idx == 0) rowptr[NN] = NE;
}

__global__ void fill_kernel(const int* __restrict__ src, const int* __restrict__ dst,
                            int* __restrict__ cursor, int* __restrict__ esrc) {
  for (int e = blockIdx.x * blockDim.x + threadIdx.x; e < NE; e += gridDim.x * blockDim.x) {
    int p = atomicAdd(&cursor[dst[e]], 1);
    esrc[p] = src[e];
  }
}

// ------------------------------------- per-graph node counts (batch sorted)
__global__ __launch_bounds__(128) void gbounds_kernel(const int* __restrict__ batch,
                                                      float* __restrict__ gcnt) {
  __shared__ int sb[NG + 1];
  const int g = threadIdx.x;
  int lo = 0, hi = NN;
  while (lo < hi) {
    const int mid = (lo + hi) >> 1;
    if (batch[mid] < g) lo = mid + 1; else hi = mid;
  }
  sb[g] = lo;
  if (g == 0) sb[NG] = NN;
  __syncthreads();
  gcnt[g] = (float)(sb[g + 1] - sb[g]);
}

// ------------------------------------------------- proj: y = x @ W1_0 (fp16)
__global__ __launch_bounds__(256) void proj_kernel(const float* __restrict__ x,
                                                   const float* __restrict__ w1,
                                                   __half* __restrict__ y) {
  __shared__ float sW[128 * 64];
  __shared__ float sX[64 * 128];
  const int t = threadIdx.x, c = t & 63, rg = t >> 6;
  for (int i = t; i < 128 * 64; i += 256) sW[i] = w1[i];
  const int ntiles = (NN + 63) / 64;
  for (int tile = blockIdx.x; tile < ntiles; tile += gridDim.x) {
    const int r0 = tile * 64, nv = min(64, NN - r0);
    __syncthreads();
    for (int i = t; i < nv * 32; i += 256)
      ((float4*)sX)[i] = ((const float4*)(x + (size_t)r0 * 128))[i];
    __syncthreads();
    float acc[16];
#pragma unroll
    for (int i = 0; i < 16; ++i) acc[i] = 0.f;
    for (int k = 0; k < 128; k += 4) {
      const float w0 = sW[(k + 0) * 64 + c], w1v = sW[(k + 1) * 64 + c],
                  w2v = sW[(k + 2) * 64 + c], w3v = sW[(k + 3) * 64 + c];
#pragma unroll
      for (int i = 0; i < 16; ++i) {
        const float4 xv = *(const float4*)&sX[(rg * 16 + i) * 128 + k];
        acc[i] = fmaf(xv.x, w0, acc[i]);
        acc[i] = fmaf(xv.y, w1v, acc[i]);
        acc[i] = fmaf(xv.z, w2v, acc[i]);
        acc[i] = fmaf(xv.w, w3v, acc[i]);
      }
    }
#pragma unroll
    for (int i = 0; i < 16; ++i) {
      const int r = rg * 16 + i;
      if (r < nv) y[(size_t)(r0 + r) * 64 + c] = __float2half(acc[i]);
    }
  }
}

// ---------------------------------------------------- gather: z = A h + h
// h is fp16 (128B/row). Eighth-wave per edge: 8 lanes x 16B = one row; one
// VMEM instr covers 8 edges; x2 unroll = 16 row-loads in flight per wave.
__global__ __launch_bounds__(256, 8) void agg_kernel(const __half* __restrict__ h,
                                                     const int* __restrict__ rowptr,
                                                     const int* __restrict__ esrc,
                                                     float* __restrict__ z) {
  const int ln = threadIdx.x & 63, wv = threadIdx.x >> 6;
  const int oct = ln >> 3, i = ln & 7;  // lane covers channels [i*8, i*8+8)
  const int row = blockIdx.x * 4 + wv;
  if (row >= NN) return;
  const int beg = rowptr[row], end = rowptr[row + 1];
  union H8 { float4 f; __half2 h2[4]; };
  float acc[8];
  if (oct == 0) {  // self term
    H8 u; u.f = *(const float4*)(h + (size_t)row * 64 + i * 8);
#pragma unroll
    for (int k = 0; k < 4; ++k) {
      const float2 f = __half22float2(u.h2[k]);
      acc[2 * k] = f.x; acc[2 * k + 1] = f.y;
    }
  } else {
#pragma unroll
    for (int k = 0; k < 8; ++k) acc[k] = 0.f;
  }
  int e = beg + oct;
  for (; e + 8 < end; e += 16) {
    const int s0 = esrc[e], s1 = esrc[e + 8];
    H8 u0, u1;
    u0.f = *(const float4*)(h + (size_t)s0 * 64 + i * 8);
    u1.f = *(const float4*)(h + (size_t)s1 * 64 + i * 8);
#pragma unroll
    for (int k = 0; k < 4; ++k) {
      const float2 f0 = __half22float2(u0.h2[k]);
      const float2 f1 = __half22float2(u1.h2[k]);
      acc[2 * k]     += f0.x + f1.x;
      acc[2 * k + 1] += f0.y + f1.y;
    }
  }
  for (; e < end; e += 8) {
    const int s0 = esrc[e];
    H8 u0;
    u0.f = *(const float4*)(h + (size_t)s0 * 64 + i * 8);
#pragma unroll
    for (int k = 0; k < 4; ++k) {
      const float2 f0 = __half22float2(u0.h2[k]);
      acc[2 * k] += f0.x; acc[2 * k + 1] += f0.y;
    }
  }
#pragma unroll
  for (int off = 8; off < 64; off <<= 1) {
#pragma unroll
    for (int k = 0; k < 8; ++k) acc[k] += __shfl_xor(acc[k], off);
  }
  if (oct == 0) {
    const float4 lo = {acc[0], acc[1], acc[2], acc[3]};
    const float4 hi = {acc[4], acc[5], acc[6], acc[7]};
    *(float4*)(z + (size_t)row * 64 + i * 8) = lo;
    *(float4*)(z + (size_t)row * 64 + i * 8 + 4) = hi;
  }
}

// ------------------------- MLP per layer + fused run-length pooling epilogue
// Wave-local: each wave owns a 16-row tile, private LDS slice, NO barriers.
// h = relu(relu(z@W1+b1)@W2+b2)  (layer 0 pre-projected: h1 = relu(z+b1))
// epilogue: gl[batch[n]] += h[n] (fp32, pre-quantization); hout fp16.
template <bool HASW1, bool WRITEH>
__global__ __launch_bounds__(256) void mlp_kernel(
    const float* __restrict__ z, const float* __restrict__ w1,
    const float* __restrict__ b1, const float* __restrict__ w2,
    const float* __restrict__ b2, __half* __restrict__ hout,
    const int* __restrict__ batch, float* __restrict__ gl) {
  __shared__ float sS[4][16 * 64];  // 16KB -> 4 blocks/CU
  const int t = threadIdx.x, c = t & 63, wv = t >> 6;
  const int wg = blockIdx.x * 4 + wv;
  if (wg >= NTILE) return;  // no barriers anywhere: safe
  float* slice = &sS[wv][0];
  const int n0 = wg * 16;
  const float b1c = b1[c], b2c = b2[c];

  float zr[16];
#pragma unroll
  for (int r = 0; r < 16; ++r) zr[r] = z[(size_t)(n0 + r) * 64 + c];
  if (!HASW1) {
#pragma unroll
    for (int r = 0; r < 16; ++r) zr[r] = fmaxf(zr[r] + b1c, 0.f);
  }
#pragma unroll
  for (int r = 0; r < 16; ++r) slice[r * 64 + c] = zr[r];

  if (HASW1) {
    float acc[16];
#pragma unroll
    for (int r = 0; r < 16; ++r) acc[r] = b1c;
    for (int kc = 0; kc < 4; ++kc) {
      float wr[16];
#pragma unroll
      for (int j = 0; j < 16; ++j) wr[j] = w1[(kc * 16 + j) * 64 + c];
#pragma unroll
      for (int r = 0; r < 16; ++r) {
        const float* zp = &slice[r * 64 + kc * 16];
        const float4 za = *(const float4*)(zp + 0);
        const float4 zb = *(const float4*)(zp + 4);
        const float4 zc = *(const float4*)(zp + 8);
        const float4 zd = *(const float4*)(zp + 12);
        float a = acc[r];
        a = fmaf(za.x, wr[0], a);  a = fmaf(za.y, wr[1], a);
        a = fmaf(za.z, wr[2], a);  a = fmaf(za.w, wr[3], a);
        a = fmaf(zb.x, wr[4], a);  a = fmaf(zb.y, wr[5], a);
        a = fmaf(zb.z, wr[6], a);  a = fmaf(zb.w, wr[7], a);
        a = fmaf(zc.x, wr[8], a);  a = fmaf(zc.y, wr[9], a);
        a = fmaf(zc.z, wr[10], a); a = fmaf(zc.w, wr[11], a);
        a = fmaf(zd.x, wr[12], a); a = fmaf(zd.y, wr[13], a);
        a = fmaf(zd.z, wr[14], a); a = fmaf(zd.w, wr[15], a);
        acc[r] = a;
      }
    }
#pragma unroll
    for (int r = 0; r < 16; ++r) slice[r * 64 + c] = fmaxf(acc[r], 0.f);
  }

  float acc2[16];
#pragma unroll
  for (int r = 0; r < 16; ++r) acc2[r] = b2c;
  for (int kc = 0; kc < 4; ++kc) {
    float wr[16];
#pragma unroll
    for (int j = 0; j < 16; ++j) wr[j] = w2[(kc * 16 + j) * 64 + c];
#pragma unroll
    for (int r = 0; r < 16; ++r) {
      const float* hp = &slice[r * 64 + kc * 16];
      const float4 za = *(const float4*)(hp + 0);
      const float4 zb = *(const float4*)(hp + 4);
      const float4 zc = *(const float4*)(hp + 8);
      const float4 zd = *(const float4*)(hp + 12);
      float a = acc2[r];
      a = fmaf(za.x, wr[0], a);  a = fmaf(za.y, wr[1], a);
      a = fmaf(za.z, wr[2], a);  a = fmaf(za.w, wr[3], a);
      a = fmaf(zb.x, wr[4], a);  a = fmaf(zb.y, wr[5], a);
      a = fmaf(zb.z, wr[6], a);  a = fmaf(zb.w, wr[7], a);
      a = fmaf(zc.x, wr[8], a);  a = fmaf(zc.y, wr[9], a);
      a = fmaf(zc.z, wr[10], a); a = fmaf(zc.w, wr[11], a);
      a = fmaf(zd.x, wr[12], a); a = fmaf(zd.y, wr[13], a);
      a = fmaf(zd.z, wr[14], a); a = fmaf(zd.w, wr[15], a);
      acc2[r] = a;
    }
  }
  // store (fp16) + fused pooling (run-length over sorted batch)
  float pacc = 0.f;
  int cur = batch[n0];
#pragma unroll
  for (int r = 0; r < 16; ++r) {
    const float hval = fmaxf(acc2[r], 0.f);
    if (WRITEH) hout[(size_t)(n0 + r) * 64 + c] = __float2half(hval);
    const int b = batch[n0 + r];
    if (b != cur) {
      atomicAdd(&gl[(size_t)cur * 64 + c], pacc);
      pacc = 0.f;
      cur = b;
    }
    pacc += hval;
  }
  atomicAdd(&gl[(size_t)cur * 64 + c], pacc);
}

// ---------------------- JK fold + first classifier matvec (1 graph / block)
__global__ __launch_bounds__(64) void jk_fold_kernel(
    const float* __restrict__ g5, const float* __restrict__ gcnt,
    const float* __restrict__ jkw, const float* __restrict__ jkb,
    const float* __restrict__ w1, const float* __restrict__ b1,
    float* __restrict__ tmat) {
  __shared__ float sg[64];
  const int gi = blockIdx.x, c = threadIdx.x;
  float a = jkb[c] * gcnt[gi];
  for (int l = 0; l < 5; ++l) {
    const float* gv = &g5[(size_t)(l * NG + gi) * 64];
    const float* wv = &jkw[(size_t)l * 64 * 64];
#pragma unroll 8
    for (int k = 0; k < 64; ++k) a = fmaf(gv[k], wv[k * 64 + c], a);
  }
  sg[c] = a;
  __syncthreads();
  float tv = b1[c];
#pragma unroll 8
  for (int k = 0; k < 64; ++k) tv = fmaf(sg[k], w1[k * 64 + c], tv);
  tmat[gi * 64 + c] = tv;
}

// --------------------------------------------- BN (batch stats) + out matvec
__global__ __launch_bounds__(256) void bn_out_kernel(
    const float* __restrict__ tmat, const float* __restrict__ gamma,
    const float* __restrict__ beta, const float* __restrict__ w2,
    const float* __restrict__ b2, float* __restrict__ out) {
  __shared__ float sT[NG * 64];
  __shared__ float sW2[64 * OUTC];
  __shared__ float sMu[64], sRs[64];
  const int t = threadIdx.x;
  for (int i = t; i < NG * 64; i += 256) sT[i] = tmat[i];
  for (int i = t; i < 64 * OUTC; i += 256) sW2[i] = w2[i];
  __syncthreads();
  if (t < 64) {
    float s = 0.f;
    for (int gi = 0; gi < NG; ++gi) s += sT[gi * 64 + t];
    const float mu = s / NG;
    float v = 0.f;
    for (int gi = 0; gi < NG; ++gi) { const float d = sT[gi * 64 + t] - mu; v += d * d; }
    v /= NG;
    sMu[t] = mu;
    sRs[t] = rsqrtf(v + 1e-5f);
  }
  __syncthreads();
  for (int idx = t; idx < NG * 64; idx += 256) {
    const int cc = idx & 63;
    sT[idx] = fmaxf((sT[idx] - sMu[cc]) * sRs[cc] * gamma[cc] + beta[cc], 0.f);
  }
  __syncthreads();
  for (int idx = t; idx < NG * OUTC; idx += 256) {
    const int gi = idx / OUTC, o = idx % OUTC;
    float a = b2[o];
    for (int k = 0; k < 64; ++k) a = fmaf(sT[gi * 64 + k], sW2[k * OUTC + o], a);
    out[idx] = a;
  }
}

// ---------------------------------------------------------------- launch
extern "C" void kernel_launch(void* const* d_in, const int* in_sizes, int n_in,
                              void* d_out, int out_size, void* d_ws, size_t ws_size,
                              hipStream_t stream) {
  const float* x     = (const float*)d_in[0];
  const int*   ei    = (const int*)d_in[1];
  const int*   batch = (const int*)d_in[2];
  const float* w1_0  = (const float*)d_in[3];
  const float* b1_0  = (const float*)d_in[4];
  const float* w2_0  = (const float*)d_in[5];
  const float* b2_0  = (const float*)d_in[6];
  const float* w1_r  = (const float*)d_in[7];
  const float* b1_r  = (const float*)d_in[8];
  const float* w2_r  = (const float*)d_in[9];
  const float* b2_r  = (const float*)d_in[10];
  const float* jk_w  = (const float*)d_in[11];
  const float* jk_b  = (const float*)d_in[12];
  const float* cw1   = (const float*)d_in[13];
  const float* cb1   = (const float*)d_in[14];
  const float* bng   = (const float*)d_in[15];
  const float* bnb   = (const float*)d_in[16];
  const float* cw2   = (const float*)d_in[17];
  const float* cb2   = (const float*)d_in[18];
  float* out = (float*)d_out;

  char* base = (char*)d_ws;
  size_t o = 0;
  auto take = [&](size_t n) { char* p = base + o; o = (o + n + 255) & ~(size_t)255; return p; };
  int*    cnt    = (int*)take((size_t)NN * 4);
  int*    rowptr = (int*)take((size_t)(NN + 1) * 4);
  int*    cursor = (int*)take((size_t)NN * 4);
  int*    part   = (int*)take((size_t)SCAN_NB * 4);
  int*    esrc   = (int*)take((size_t)NE * 4);
  __half* hA     = (__half*)take((size_t)NN * 64 * 2);
  __half* hB     = (__half*)take((size_t)NN * 64 * 2);
  float*  z      = (float*)take((size_t)NN * 64 * 4);
  float*  g5     = (float*)take((size_t)5 * NG * 64 * 4);
  float*  gcnt   = (float*)take((size_t)NG * 4);
  float*  tmat   = (float*)take((size_t)NG * 64 * 4);
  (void)ws_size; (void)in_sizes; (void)n_in; (void)out_size;

  hipMemsetAsync(cnt, 0, (size_t)NN * 4, stream);
  hipMemsetAsync(g5, 0, (size_t)5 * NG * 64 * 4, stream);

  const int* src = ei;
  const int* dst = ei + NE;
  count_kernel<<<1024, 256, 0, stream>>>(dst, cnt);
  partial_kernel<<<SCAN_NB, 256, 0, stream>>>(cnt, part);
  scanpart_kernel<<<1, 256, 0, stream>>>(part);
  scatter_scan_kernel<<<SCAN_NB, 256, 0, stream>>>(cnt, part, rowptr, cursor);
  fill_kernel<<<1024, 256, 0, stream>>>(src, dst, cursor, esrc);
  gbounds_kernel<<<1, 128, 0, stream>>>(batch, gcnt);

  const int MLP_GRID = (NTILE + 3) / 4;  // 782

  // layer 0 (pre-projected): y = x@W1_0 (into hB fp16), z = A y + y, MLP w/o W1
  proj_kernel<<<512, 256, 0, stream>>>(x, w1_0, hB);
  agg_kernel<<<(NN + 3) / 4, 256, 0, stream>>>(hB, rowptr, esrc, z);
  mlp_kernel<false, true><<<MLP_GRID, 256, 0, stream>>>(z, nullptr, b1_0, w2_0, b2_0,
                                                        hA, batch, g5);
  const __half* hin = hA;
  __half* hout = hB;
  for (int l = 1; l < 5; ++l) {
    agg_kernel<<<(NN + 3) / 4, 256, 0, stream>>>(hin, rowptr, esrc, z);
    if (l < 4) {
      mlp_kernel<true, true><<<MLP_GRID, 256, 0, stream>>>(
          z, w1_r + (size_t)(l - 1) * 64 * 64, b1_r + (size_t)(l - 1) * 64,
          w2_r + (size_t)(l - 1) * 64 * 64, b2_r + (size_t)(l - 1) * 64, hout,
          batch, g5 + (size_t)l * NG * 64);
    } else {
      // last layer: h5 is only pooled -> skip the dead hout store
      mlp_kernel<true, false><<<MLP_GRID, 256, 0, stream>>>(
          z, w1_r + (size_t)(l - 1) * 64 * 64, b1_r + (size_t)(l - 1) * 64,
          w2_r + (size_t)(l - 1) * 64 * 64, b2_r + (size_t)(l - 1) * 64, hout,
          batch, g5 + (size_t)l * NG * 64);
    }
    __half* tmp = (__half*)hin;
    hin = hout;
    hout = tmp;
  }

  jk_fold_kernel<<<NG, 64, 0, stream>>>(g5, gcnt, jk_w, jk_b, cw1, cb1, tmat);
  bn_out_kernel<<<1, 256, 0, stream>>>(tmat, bng, bnb, cw2, cb2, out);
}

// Round 7
// 427.632 us; speedup vs baseline: 2.7620x; 1.0543x over previous
//
#include <hip/hip_runtime.h>
#include <hip/hip_fp16.h>

#define NN 50000
#define NE 800000
#define NG 128
#define OUTC 10
#define SCAN_NB ((NN + 255) / 256)  // 196
#define NTILE 3125                  // 50000 / 16 exactly

// ---------------------------------------------------------------- CSR build
__global__ void count_kernel(const int* __restrict__ dst, int* __restrict__ cnt) {
  for (int e = blockIdx.x * blockDim.x + threadIdx.x; e < NE; e += gridDim.x * blockDim.x)
    atomicAdd(&cnt[dst[e]], 1);
}

__global__ __launch_bounds__(256) void partial_kernel(const int* __restrict__ cnt,
                                                      int* __restrict__ part) {
  __shared__ int red[256];
  const int t = threadIdx.x;
  const int idx = blockIdx.x * 256 + t;
  red[t] = (idx < NN) ? cnt[idx] : 0;
  __syncthreads();
#pragma unroll
  for (int off = 128; off > 0; off >>= 1) {
    if (t < off) red[t] += red[t + off];
    __syncthreads();
  }
  if (t == 0) part[blockIdx.x] = red[0];
}

__global__ __launch_bounds__(256) void scanpart_kernel(int* __restrict__ part) {
  __shared__ int s[256];
  const int t = threadIdx.x;
  s[t] = (t < SCAN_NB) ? part[t] : 0;
  __syncthreads();
#pragma unroll
  for (int off = 1; off < 256; off <<= 1) {
    const int v = (t >= off) ? s[t - off] : 0;
    __syncthreads();
    s[t] += v;
    __syncthreads();
  }
  if (t < SCAN_NB) part[t] = (t == 0) ? 0 : s[t - 1];
}

__global__ __launch_bounds__(256) void scatter_scan_kernel(const int* __restrict__ cnt,
                                                           const int* __restrict__ part,
                                                           int* __restrict__ rowptr,
                                                           int* __restrict__ cursor) {
  __shared__ int s[256];
  const int t = threadIdx.x;
  const int idx = blockIdx.x * 256 + t;
  s[t] = (idx < NN) ? cnt[idx] : 0;
  __syncthreads();
#pragma unroll
  for (int off = 1; off < 256; off <<= 1) {
    const int v = (t >= off) ? s[t - off] : 0;
    __syncthreads();
    s[t] += v;
    __syncthreads();
  }
  const int excl = part[blockIdx.x] + ((t == 0) ? 0 : s[t - 1]);
  if (idx < NN) { rowptr[idx] = excl; cursor[idx] = excl; }
  if (idx == 0) rowptr[NN] = NE;
}

__global__ void fill_kernel(const int* __restrict__ src, const int* __restrict__ dst,
                            int* __restrict__ cursor, int* __restrict__ esrc) {
  for (int e = blockIdx.x * blockDim.x + threadIdx.x; e < NE; e += gridDim.x * blockDim.x) {
    int p = atomicAdd(&cursor[dst[e]], 1);
    esrc[p] = src[e];
  }
}

// ------------------------------------- per-graph node counts (batch sorted)
__global__ __launch_bounds__(128) void gbounds_kernel(const int* __restrict__ batch,
                                                      float* __restrict__ gcnt) {
  __shared__ int sb[NG + 1];
  const int g = threadIdx.x;
  int lo = 0, hi = NN;
  while (lo < hi) {
    const int mid = (lo + hi) >> 1;
    if (batch[mid] < g) lo = mid + 1; else hi = mid;
  }
  sb[g] = lo;
  if (g == 0) sb[NG] = NN;
  __syncthreads();
  gcnt[g] = (float)(sb[g + 1] - sb[g]);
}

// ------------------------------------------------- proj: y = x @ W1_0 (fp16)
__global__ __launch_bounds__(256) void proj_kernel(const float* __restrict__ x,
                                                   const float* __restrict__ w1,
                                                   __half* __restrict__ y) {
  __shared__ float sW[128 * 64];
  __shared__ float sX[64 * 128];
  const int t = threadIdx.x, c = t & 63, rg = t >> 6;
  for (int i = t; i < 128 * 64; i += 256) sW[i] = w1[i];
  const int ntiles = (NN + 63) / 64;
  for (int tile = blockIdx.x; tile < ntiles; tile += gridDim.x) {
    const int r0 = tile * 64, nv = min(64, NN - r0);
    __syncthreads();
    for (int i = t; i < nv * 32; i += 256)
      ((float4*)sX)[i] = ((const float4*)(x + (size_t)r0 * 128))[i];
    __syncthreads();
    float acc[16];
#pragma unroll
    for (int i = 0; i < 16; ++i) acc[i] = 0.f;
    for (int k = 0; k < 128; k += 4) {
      const float w0 = sW[(k + 0) * 64 + c], w1v = sW[(k + 1) * 64 + c],
                  w2v = sW[(k + 2) * 64 + c], w3v = sW[(k + 3) * 64 + c];
#pragma unroll
      for (int i = 0; i < 16; ++i) {
        const float4 xv = *(const float4*)&sX[(rg * 16 + i) * 128 + k];
        acc[i] = fmaf(xv.x, w0, acc[i]);
        acc[i] = fmaf(xv.y, w1v, acc[i]);
        acc[i] = fmaf(xv.z, w2v, acc[i]);
        acc[i] = fmaf(xv.w, w3v, acc[i]);
      }
    }
#pragma unroll
    for (int i = 0; i < 16; ++i) {
      const int r = rg * 16 + i;
      if (r < nv) y[(size_t)(r0 + r) * 64 + c] = __float2half(acc[i]);
    }
  }
}

// --------------------------------------- FUSED GIN layer: gather + MLP + pool
// Wave owns 16 rows. Gather: 8 octets x 8 lanes; octet o owns rows {2o,2o+1},
// its 8 lanes cover all 64 channels (16B fp16/lane/edge) -> no cross-octet
// reduction. z -> private LDS slice -> wave-local matvecs (no barriers).
// h = relu(relu(z@W1+b1)@W2+b2)  (HASW1=false: h1 = relu(z+b1), layer 0)
// epilogue: run-length pooled atomics into gl; hout fp16 unless !WRITEH.
template <bool HASW1, bool WRITEH>
__global__ __launch_bounds__(256) void gin_fused_kernel(
    const __half* __restrict__ hin, const int* __restrict__ rowptr,
    const int* __restrict__ esrc,
    const float* __restrict__ w1, const float* __restrict__ b1,
    const float* __restrict__ w2, const float* __restrict__ b2,
    __half* __restrict__ hout, const int* __restrict__ batch,
    float* __restrict__ gl) {
  __shared__ float sS[4][16 * 64];  // 16KB/block
  const int t = threadIdx.x, c = t & 63, wv = t >> 6;
  const int wg = blockIdx.x * 4 + wv;
  if (wg >= NTILE) return;  // no barriers anywhere: safe
  float* slice = &sS[wv][0];
  const int n0 = wg * 16;
  const int oct = c >> 3, i = c & 7;  // lane covers channels [i*8, i*8+8)

  // ---- gather phase: rows rA = n0+2*oct, rB = rA+1
  const int rA = n0 + 2 * oct;
  const int pA0 = rowptr[rA], pA1 = rowptr[rA + 1], pB1 = rowptr[rA + 2];
  union H8 { float4 f; __half2 h2[4]; };
  const __half* hch = hin + i * 8;
  float zA[8], zB[8];
  {
    H8 u0, u1;
    u0.f = *(const float4*)(hch + (size_t)rA * 64);
    u1.f = *(const float4*)(hch + (size_t)(rA + 1) * 64);
#pragma unroll
    for (int k = 0; k < 4; ++k) {
      const float2 f0 = __half22float2(u0.h2[k]);
      const float2 f1 = __half22float2(u1.h2[k]);
      zA[2 * k] = f0.x; zA[2 * k + 1] = f0.y;
      zB[2 * k] = f1.x; zB[2 * k + 1] = f1.y;
    }
  }
  int e = pA0;
  for (; e + 1 < pA1; e += 2) {
    const int s0 = esrc[e], s1 = esrc[e + 1];
    H8 u0, u1;
    u0.f = *(const float4*)(hch + (size_t)s0 * 64);
    u1.f = *(const float4*)(hch + (size_t)s1 * 64);
#pragma unroll
    for (int k = 0; k < 4; ++k) {
      const float2 f0 = __half22float2(u0.h2[k]);
      const float2 f1 = __half22float2(u1.h2[k]);
      zA[2 * k]     += f0.x + f1.x;
      zA[2 * k + 1] += f0.y + f1.y;
    }
  }
  if (e < pA1) {
    H8 u0; u0.f = *(const float4*)(hch + (size_t)esrc[e] * 64);
#pragma unroll
    for (int k = 0; k < 4; ++k) {
      const float2 f0 = __half22float2(u0.h2[k]);
      zA[2 * k] += f0.x; zA[2 * k + 1] += f0.y;
    }
  }
  e = pA1;
  for (; e + 1 < pB1; e += 2) {
    const int s0 = esrc[e], s1 = esrc[e + 1];
    H8 u0, u1;
    u0.f = *(const float4*)(hch + (size_t)s0 * 64);
    u1.f = *(const float4*)(hch + (size_t)s1 * 64);
#pragma unroll
    for (int k = 0; k < 4; ++k) {
      const float2 f0 = __half22float2(u0.h2[k]);
      const float2 f1 = __half22float2(u1.h2[k]);
      zB[2 * k]     += f0.x + f1.x;
      zB[2 * k + 1] += f0.y + f1.y;
    }
  }
  if (e < pB1) {
    H8 u0; u0.f = *(const float4*)(hch + (size_t)esrc[e] * 64);
#pragma unroll
    for (int k = 0; k < 4; ++k) {
      const float2 f0 = __half22float2(u0.h2[k]);
      zB[2 * k] += f0.x; zB[2 * k + 1] += f0.y;
    }
  }
  if (!HASW1) {  // layer 0 (pre-projected): h1 = relu(z + b1) fused here
    const float4 blo = *(const float4*)(b1 + i * 8);
    const float4 bhi = *(const float4*)(b1 + i * 8 + 4);
    zA[0] = fmaxf(zA[0] + blo.x, 0.f); zA[1] = fmaxf(zA[1] + blo.y, 0.f);
    zA[2] = fmaxf(zA[2] + blo.z, 0.f); zA[3] = fmaxf(zA[3] + blo.w, 0.f);
    zA[4] = fmaxf(zA[4] + bhi.x, 0.f); zA[5] = fmaxf(zA[5] + bhi.y, 0.f);
    zA[6] = fmaxf(zA[6] + bhi.z, 0.f); zA[7] = fmaxf(zA[7] + bhi.w, 0.f);
    zB[0] = fmaxf(zB[0] + blo.x, 0.f); zB[1] = fmaxf(zB[1] + blo.y, 0.f);
    zB[2] = fmaxf(zB[2] + blo.z, 0.f); zB[3] = fmaxf(zB[3] + blo.w, 0.f);
    zB[4] = fmaxf(zB[4] + bhi.x, 0.f); zB[5] = fmaxf(zB[5] + bhi.y, 0.f);
    zB[6] = fmaxf(zB[6] + bhi.z, 0.f); zB[7] = fmaxf(zB[7] + bhi.w, 0.f);
  }
  {
    const float4 a0 = {zA[0], zA[1], zA[2], zA[3]};
    const float4 a1 = {zA[4], zA[5], zA[6], zA[7]};
    const float4 b0v = {zB[0], zB[1], zB[2], zB[3]};
    const float4 b1v_ = {zB[4], zB[5], zB[6], zB[7]};
    *(float4*)&slice[(2 * oct) * 64 + i * 8] = a0;
    *(float4*)&slice[(2 * oct) * 64 + i * 8 + 4] = a1;
    *(float4*)&slice[(2 * oct + 1) * 64 + i * 8] = b0v;
    *(float4*)&slice[(2 * oct + 1) * 64 + i * 8 + 4] = b1v_;
  }
  // same-wave LDS: DS pipe is in-order per wave (same pattern as prior mlp)

  const float b1c = b1[c], b2c = b2[c];
  // ---- matvec1: h1 = relu(z @ W1 + b1)
  if (HASW1) {
    float acc[16];
#pragma unroll
    for (int r = 0; r < 16; ++r) acc[r] = b1c;
    for (int kc = 0; kc < 4; ++kc) {
      float wr[16];
#pragma unroll
      for (int j = 0; j < 16; ++j) wr[j] = w1[(kc * 16 + j) * 64 + c];
#pragma unroll
      for (int r = 0; r < 16; ++r) {
        const float* zp = &slice[r * 64 + kc * 16];
        const float4 za = *(const float4*)(zp + 0);
        const float4 zb = *(const float4*)(zp + 4);
        const float4 zc = *(const float4*)(zp + 8);
        const float4 zd = *(const float4*)(zp + 12);
        float a = acc[r];
        a = fmaf(za.x, wr[0], a);  a = fmaf(za.y, wr[1], a);
        a = fmaf(za.z, wr[2], a);  a = fmaf(za.w, wr[3], a);
        a = fmaf(zb.x, wr[4], a);  a = fmaf(zb.y, wr[5], a);
        a = fmaf(zb.z, wr[6], a);  a = fmaf(zb.w, wr[7], a);
        a = fmaf(zc.x, wr[8], a);  a = fmaf(zc.y, wr[9], a);
        a = fmaf(zc.z, wr[10], a); a = fmaf(zc.w, wr[11], a);
        a = fmaf(zd.x, wr[12], a); a = fmaf(zd.y, wr[13], a);
        a = fmaf(zd.z, wr[14], a); a = fmaf(zd.w, wr[15], a);
        acc[r] = a;
      }
    }
#pragma unroll
    for (int r = 0; r < 16; ++r) slice[r * 64 + c] = fmaxf(acc[r], 0.f);
  }

  // ---- matvec2: h = relu(h1 @ W2 + b2)
  float acc2[16];
#pragma unroll
  for (int r = 0; r < 16; ++r) acc2[r] = b2c;
  for (int kc = 0; kc < 4; ++kc) {
    float wr[16];
#pragma unroll
    for (int j = 0; j < 16; ++j) wr[j] = w2[(kc * 16 + j) * 64 + c];
#pragma unroll
    for (int r = 0; r < 16; ++r) {
      const float* hp = &slice[r * 64 + kc * 16];
      const float4 za = *(const float4*)(hp + 0);
      const float4 zb = *(const float4*)(hp + 4);
      const float4 zc = *(const float4*)(hp + 8);
      const float4 zd = *(const float4*)(hp + 12);
      float a = acc2[r];
      a = fmaf(za.x, wr[0], a);  a = fmaf(za.y, wr[1], a);
      a = fmaf(za.z, wr[2], a);  a = fmaf(za.w, wr[3], a);
      a = fmaf(zb.x, wr[4], a);  a = fmaf(zb.y, wr[5], a);
      a = fmaf(zb.z, wr[6], a);  a = fmaf(zb.w, wr[7], a);
      a = fmaf(zc.x, wr[8], a);  a = fmaf(zc.y, wr[9], a);
      a = fmaf(zc.z, wr[10], a); a = fmaf(zc.w, wr[11], a);
      a = fmaf(zd.x, wr[12], a); a = fmaf(zd.y, wr[13], a);
      a = fmaf(zd.z, wr[14], a); a = fmaf(zd.w, wr[15], a);
      acc2[r] = a;
    }
  }
  // ---- store (fp16) + fused run-length pooling over sorted batch
  float pacc = 0.f;
  int cur = batch[n0];
#pragma unroll
  for (int r = 0; r < 16; ++r) {
    const float hval = fmaxf(acc2[r], 0.f);
    if (WRITEH) hout[(size_t)(n0 + r) * 64 + c] = __float2half(hval);
    const int b = batch[n0 + r];
    if (b != cur) {
      atomicAdd(&gl[(size_t)cur * 64 + c], pacc);
      pacc = 0.f;
      cur = b;
    }
    pacc += hval;
  }
  atomicAdd(&gl[(size_t)cur * 64 + c], pacc);
}

// ---------------------- JK fold + first classifier matvec (1 graph / block)
__global__ __launch_bounds__(64) void jk_fold_kernel(
    const float* __restrict__ g5, const float* __restrict__ gcnt,
    const float* __restrict__ jkw, const float* __restrict__ jkb,
    const float* __restrict__ w1, const float* __restrict__ b1,
    float* __restrict__ tmat) {
  __shared__ float sg[64];
  const int gi = blockIdx.x, c = threadIdx.x;
  float a = jkb[c] * gcnt[gi];
  for (int l = 0; l < 5; ++l) {
    const float* gv = &g5[(size_t)(l * NG + gi) * 64];
    const float* wv = &jkw[(size_t)l * 64 * 64];
#pragma unroll 8
    for (int k = 0; k < 64; ++k) a = fmaf(gv[k], wv[k * 64 + c], a);
  }
  sg[c] = a;
  __syncthreads();
  float tv = b1[c];
#pragma unroll 8
  for (int k = 0; k < 64; ++k) tv = fmaf(sg[k], w1[k * 64 + c], tv);
  tmat[gi * 64 + c] = tv;
}

// --------------------------------------------- BN (batch stats) + out matvec
__global__ __launch_bounds__(256) void bn_out_kernel(
    const float* __restrict__ tmat, const float* __restrict__ gamma,
    const float* __restrict__ beta, const float* __restrict__ w2,
    const float* __restrict__ b2, float* __restrict__ out) {
  __shared__ float sT[NG * 64];
  __shared__ float sW2[64 * OUTC];
  __shared__ float sMu[64], sRs[64];
  const int t = threadIdx.x;
  for (int i = t; i < NG * 64; i += 256) sT[i] = tmat[i];
  for (int i = t; i < 64 * OUTC; i += 256) sW2[i] = w2[i];
  __syncthreads();
  if (t < 64) {
    float s = 0.f;
    for (int gi = 0; gi < NG; ++gi) s += sT[gi * 64 + t];
    const float mu = s / NG;
    float v = 0.f;
    for (int gi = 0; gi < NG; ++gi) { const float d = sT[gi * 64 + t] - mu; v += d * d; }
    v /= NG;
    sMu[t] = mu;
    sRs[t] = rsqrtf(v + 1e-5f);
  }
  __syncthreads();
  for (int idx = t; idx < NG * 64; idx += 256) {
    const int cc = idx & 63;
    sT[idx] = fmaxf((sT[idx] - sMu[cc]) * sRs[cc] * gamma[cc] + beta[cc], 0.f);
  }
  __syncthreads();
  for (int idx = t; idx < NG * OUTC; idx += 256) {
    const int gi = idx / OUTC, o = idx % OUTC;
    float a = b2[o];
    for (int k = 0; k < 64; ++k) a = fmaf(sT[gi * 64 + k], sW2[k * OUTC + o], a);
    out[idx] = a;
  }
}

// ---------------------------------------------------------------- launch
extern "C" void kernel_launch(void* const* d_in, const int* in_sizes, int n_in,
                              void* d_out, int out_size, void* d_ws, size_t ws_size,
                              hipStream_t stream) {
  const float* x     = (const float*)d_in[0];
  const int*   ei    = (const int*)d_in[1];
  const int*   batch = (const int*)d_in[2];
  const float* w1_0  = (const float*)d_in[3];
  const float* b1_0  = (const float*)d_in[4];
  const float* w2_0  = (const float*)d_in[5];
  const float* b2_0  = (const float*)d_in[6];
  const float* w1_r  = (const float*)d_in[7];
  const float* b1_r  = (const float*)d_in[8];
  const float* w2_r  = (const float*)d_in[9];
  const float* b2_r  = (const float*)d_in[10];
  const float* jk_w  = (const float*)d_in[11];
  const float* jk_b  = (const float*)d_in[12];
  const float* cw1   = (const float*)d_in[13];
  const float* cb1   = (const float*)d_in[14];
  const float* bng   = (const float*)d_in[15];
  const float* bnb   = (const float*)d_in[16];
  const float* cw2   = (const float*)d_in[17];
  const float* cb2   = (const float*)d_in[18];
  float* out = (float*)d_out;

  char* base = (char*)d_ws;
  size_t o = 0;
  auto take = [&](size_t n) { char* p = base + o; o = (o + n + 255) & ~(size_t)255; return p; };
  int*    cnt    = (int*)take((size_t)NN * 4);
  int*    rowptr = (int*)take((size_t)(NN + 1) * 4);
  int*    cursor = (int*)take((size_t)NN * 4);
  int*    part   = (int*)take((size_t)SCAN_NB * 4);
  int*    esrc   = (int*)take((size_t)NE * 4);
  __half* hA     = (__half*)take((size_t)NN * 64 * 2);
  __half* hB     = (__half*)take((size_t)NN * 64 * 2);
  float*  g5     = (float*)take((size_t)5 * NG * 64 * 4);
  float*  gcnt   = (float*)take((size_t)NG * 4);
  float*  tmat   = (float*)take((size_t)NG * 64 * 4);
  (void)ws_size; (void)in_sizes; (void)n_in; (void)out_size;

  hipMemsetAsync(cnt, 0, (size_t)NN * 4, stream);
  hipMemsetAsync(g5, 0, (size_t)5 * NG * 64 * 4, stream);

  const int* src = ei;
  const int* dst = ei + NE;
  count_kernel<<<1024, 256, 0, stream>>>(dst, cnt);
  partial_kernel<<<SCAN_NB, 256, 0, stream>>>(cnt, part);
  scanpart_kernel<<<1, 256, 0, stream>>>(part);
  scatter_scan_kernel<<<SCAN_NB, 256, 0, stream>>>(cnt, part, rowptr, cursor);
  fill_kernel<<<1024, 256, 0, stream>>>(src, dst, cursor, esrc);
  gbounds_kernel<<<1, 128, 0, stream>>>(batch, gcnt);

  const int GRID = (NTILE + 3) / 4;  // 782

  // layer 0 (pre-projected): y = x@W1_0 (into hB fp16), then fused w/o W1
  proj_kernel<<<512, 256, 0, stream>>>(x, w1_0, hB);
  gin_fused_kernel<false, true><<<GRID, 256, 0, stream>>>(
      hB, rowptr, esrc, nullptr, b1_0, w2_0, b2_0, hA, batch, g5);
  const __half* hin = hA;
  __half* hout = hB;
  for (int l = 1; l < 5; ++l) {
    if (l < 4) {
      gin_fused_kernel<true, true><<<GRID, 256, 0, stream>>>(
          hin, rowptr, esrc, w1_r + (size_t)(l - 1) * 64 * 64,
          b1_r + (size_t)(l - 1) * 64, w2_r + (size_t)(l - 1) * 64 * 64,
          b2_r + (size_t)(l - 1) * 64, hout, batch, g5 + (size_t)l * NG * 64);
    } else {
      // last layer: h5 is only pooled -> skip the dead hout store
      gin_fused_kernel<true, false><<<GRID, 256, 0, stream>>>(
          hin, rowptr, esrc, w1_r + (size_t)(l - 1) * 64 * 64,
          b1_r + (size_t)(l - 1) * 64, w2_r + (size_t)(l - 1) * 64 * 64,
          b2_r + (size_t)(l - 1) * 64, hout, batch, g5 + (size_t)l * NG * 64);
    }
    __half* tmp = (__half*)hin;
    hin = hout;
    hout = tmp;
  }

  jk_fold_kernel<<<NG, 64, 0, stream>>>(g5, gcnt, jk_w, jk_b, cw1, cb1, tmat);
  bn_out_kernel<<<1, 256, 0, stream>>>(tmat, bng, bnb, cw2, cb2, out);
}